// Round 4
// baseline (45854.373 us; speedup 1.0000x reference)
//
#include <hip/hip_runtime.h>

typedef __attribute__((ext_vector_type(4))) float f32x4;

// ---------------- fused conv3x3+BN+relu+conv1x1, fp32 end-to-end, NO workspace.
// A staged from sf (NCHW fp32), B staged from w1 with BN scale folded in-kernel.
__global__ __launch_bounds__(512) void conv_head_f32_k(
    const float* __restrict__ sf, const float* __restrict__ w1,
    const float* __restrict__ gamma, const float* __restrict__ beta,
    const float* __restrict__ mean, const float* __restrict__ var,
    const float* __restrict__ w2, const float* __restrict__ b2,
    float* __restrict__ out) {
  const int NOUT[6] = {4, 2, 1, 3, 2, 2};
  const int OFFS[6] = {0, 4, 6, 7, 10, 12};
  __shared__ float A_s[64 * 36];   // [64 pixels][32 ic + pad]
  __shared__ float B_s[256 * 36];  // [256 oc][32 ic + pad]
  __shared__ float s_s[256], tb_s[256];

  int tid = threadIdx.x;
  int head = blockIdx.y;
  int p_base = blockIdx.x * 64;     // 40000 % 64 == 0 -> never crosses batch
  int b = p_base / 40000;
  int p_loc = p_base - b * 40000;

  // BN fold: s = gamma*rsqrt(var+eps), tb = beta - s*mean
  if (tid < 256) {
    int hc = head * 256 + tid;
    float s = gamma[hc] * rsqrtf(var[hc] + 1e-5f);
    s_s[tid] = s;
    tb_s[tid] = beta[hc] - s * mean[hc];
  }
  __syncthreads();

  // A staging coords: thread -> (pixel row mm, 4 input channels at ci)
  int mm = tid >> 3, ci = (tid & 7) << 2;
  int p = p_loc + mm;
  int ay = p / 200;
  int ax = p - ay * 200;
  const float* sfb = sf + (size_t)b * 256 * 40000;

  // B staging coords: thread -> (oc, 16 ic's at kk)
  int oc = tid >> 1;
  int kk = (tid & 1) << 4;
  float sv = s_s[oc];
  const float* w1h = w1 + ((size_t)head * 256 + oc) * 2304; // [ic*9 + tap]

  // compute mapping: thread -> (pixel row, oc set {cbase + 8i})
  int row = tid >> 3, cbase = tid & 7;
  float acc[32];
#pragma unroll
  for (int i = 0; i < 32; ++i) acc[i] = 0.f;

  for (int kt = 0; kt < 72; ++kt) {
    int tap = kt >> 3;
    int c0 = (kt & 7) << 5;
    int t3 = tap / 3;
    int dy = t3 - 1, dx = tap - t3 * 3 - 1;
    // stage A (64 px x 32 ic, fp32, SAME-padding mask) straight from sf NCHW
    {
      int yy = ay + dy, xx = ax + dx;
      bool ok = (unsigned)yy < 200u && (unsigned)xx < 200u;
      int pix = yy * 200 + xx;
#pragma unroll
      for (int cq = 0; cq < 4; ++cq)
        A_s[mm * 36 + ci + cq] = ok ? sfb[(c0 + ci + cq) * 40000 + pix] : 0.f;
    }
    // stage B (256 oc x 32 ic, fp32, BN-scaled) straight from w1
    {
#pragma unroll
      for (int j = 0; j < 16; ++j)
        B_s[oc * 36 + kk + j] = sv * w1h[(c0 + kk + j) * 9 + tap];
    }
    __syncthreads();

    // A row into registers
    float a[32];
    {
      const f32x4* ar = (const f32x4*)&A_s[row * 36];
#pragma unroll
      for (int t = 0; t < 8; ++t) {
        f32x4 v = ar[t];
        a[4 * t] = v[0]; a[4 * t + 1] = v[1]; a[4 * t + 2] = v[2]; a[4 * t + 3] = v[3];
      }
    }
#pragma unroll
    for (int i = 0; i < 32; ++i) {
      int cc = cbase + i * 8;
      const f32x4* br = (const f32x4*)&B_s[cc * 36];
      float s = acc[i];
#pragma unroll
      for (int t = 0; t < 8; ++t) {
        f32x4 v = br[t];
        s += a[4 * t] * v[0] + a[4 * t + 1] * v[1] + a[4 * t + 2] * v[2] + a[4 * t + 3] * v[3];
      }
      acc[i] = s;
    }
    __syncthreads();
  }

  // epilogue: BN bias + relu, then 1x1 conv partials, then 8-lane shfl reduce
  int nout = NOUT[head], ooff = OFFS[head];
  float pj[4] = {0.f, 0.f, 0.f, 0.f};
#pragma unroll
  for (int i = 0; i < 32; ++i) {
    int cc = cbase + i * 8;
    float h = fmaxf(acc[i] + tb_s[cc], 0.f);
#pragma unroll
    for (int j = 0; j < 4; ++j)
      if (j < nout) pj[j] += h * w2[(ooff + j) * 256 + cc];
  }
#pragma unroll
  for (int j = 0; j < 4; ++j) {
    float v = pj[j];
    v += __shfl_xor(v, 1);
    v += __shfl_xor(v, 2);
    v += __shfl_xor(v, 4);
    pj[j] = v;
  }
  if ((tid & 7) == 0) {
    for (int j = 0; j < nout; ++j)
      out[(b * 29 + ooff + j) * 40000 + p_loc + row] = pj[j] + b2[ooff + j];
  }
}

// ---------------- targets: heatmap (max over per-box gaussians) + zero the scalar channels
__global__ void heat_k(const float* __restrict__ gt, float* __restrict__ out) {
  __shared__ float bx[128], by[128], binv[128];
  __shared__ int bcls[128];
  int b = blockIdx.y, tid = threadIdx.x;
  if (tid < 128) {
    const float* g = gt + (b * 128 + tid) * 10;
    float x = g[0], y = g[1], z = g[2];
    bool valid = fabsf(x) + fabsf(y) + fabsf(z) > 0.f;
    float gx = x / 0.1f;
    float gy = (y + 39.68f) / 0.1f;
    float fx = floorf(gx), fy = floorf(gy);
    int gxi = (int)fx, gyi = (int)fy;
    valid = valid && gxi >= 0 && gxi < 200 && gyi >= 0 && gyi < 200;
    float bw = g[3], bl = g[4];
    float sigma = fmaxf(sqrtf(bw * bw + bl * bl) * 0.5f, 2.0f) / 3.0f;
    binv[tid] = valid ? 1.f / (2.f * sigma * sigma) : -1.f;
    bx[tid] = fx;
    by[tid] = fy;
    bcls[tid] = min(max((int)g[7], 0), 3);
  }
  __syncthreads();
  int pid = blockIdx.x * 256 + tid;
  if (pid >= 40000) return;
  float py = (float)(pid / 200);
  float px = (float)(pid - (pid / 200) * 200);
  float h0 = 0.f, h1 = 0.f, h2 = 0.f, h3 = 0.f;
  for (int n = 0; n < 128; ++n) {
    float inv = binv[n];
    if (inv < 0.f) continue;
    float ddx = px - bx[n], ddy = py - by[n];
    float t = (ddx * ddx + ddy * ddy) * inv;
    if (t > 40.f) continue; // exp(-40) ~ 4e-18, below any tolerance
    float e = __expf(-t);
    int c = bcls[n];
    h0 = fmaxf(h0, c == 0 ? e : 0.f);
    h1 = fmaxf(h1, c == 1 ? e : 0.f);
    h2 = fmaxf(h2, c == 2 ? e : 0.f);
    h3 = fmaxf(h3, c == 3 ? e : 0.f);
  }
  int base = (b * 29 + 14) * 40000 + pid;
  out[base] = h0;
  out[base + 40000] = h1;
  out[base + 80000] = h2;
  out[base + 120000] = h3;
#pragma unroll
  for (int q = 0; q < 11; ++q) out[base + (4 + q) * 40000] = 0.f;
}

// ---------------- targets: serial per-batch scatter (last-write-wins semantics)
__global__ void scatter_k(const float* __restrict__ gt, float* __restrict__ out) {
  int b = threadIdx.x;
  if (b >= 4) return;
  for (int n = 0; n < 128; ++n) {
    const float* g = gt + (b * 128 + n) * 10;
    float x = g[0], y = g[1], z = g[2];
    if (!(fabsf(x) + fabsf(y) + fabsf(z) > 0.f)) continue;
    float gx = x / 0.1f;
    float gy = (y + 39.68f) / 0.1f;
    float fx = floorf(gx), fy = floorf(gy);
    int gxi = (int)fx, gyi = (int)fy;
    if (gxi < 0 || gxi >= 200 || gyi < 0 || gyi >= 200) continue;
    int base = (b * 29 + 18) * 40000 + gyi * 200 + gxi;
    out[base] = gx - fx;
    out[base + 1 * 40000] = gy - fy;
    out[base + 2 * 40000] = z;
    out[base + 3 * 40000] = g[3];
    out[base + 4 * 40000] = g[4];
    out[base + 5 * 40000] = g[5];
    out[base + 6 * 40000] = sinf(g[6]);
    out[base + 7 * 40000] = cosf(g[6]);
    out[base + 8 * 40000] = g[8];
    out[base + 9 * 40000] = g[9];
    out[base + 10 * 40000] = 1.f;
  }
}

extern "C" void kernel_launch(void* const* d_in, const int* in_sizes, int n_in,
                              void* d_out, int out_size, void* d_ws, size_t ws_size,
                              hipStream_t stream) {
  const float* sf    = (const float*)d_in[0];
  const float* gt    = (const float*)d_in[1];
  const float* w1    = (const float*)d_in[2];
  const float* gamma = (const float*)d_in[3];
  const float* beta  = (const float*)d_in[4];
  const float* mean  = (const float*)d_in[5];
  const float* var   = (const float*)d_in[6];
  const float* w2    = (const float*)d_in[7];
  const float* b2    = (const float*)d_in[8];
  float* out = (float*)d_out;
  (void)d_ws; (void)ws_size;  // workspace deliberately unused this round

  conv_head_f32_k<<<dim3(2500, 6), 512, 0, stream>>>(sf, w1, gamma, beta, mean, var, w2, b2, out);
  heat_k<<<dim3(157, 4), 256, 0, stream>>>(gt, out);
  scatter_k<<<1, 64, 0, stream>>>(gt, out);
}